// Round 12
// baseline (72.845 us; speedup 1.0000x reference)
//
#include <hip/hip_runtime.h>

typedef float v2f __attribute__((ext_vector_type(2)));
typedef unsigned int v2u __attribute__((ext_vector_type(2)));

#define IN_DIM 32768
#define BATCH 2048
#define CLASSES 10
#define NC 2                                  // column chunks (R10 base)
#define RB 4                                  // rows per block
#define TPB 256
#define VEC 2                                 // columns per thread per j
#define COLS_PER_CHUNK (IN_DIM / NC)          // 16384
#define COLS_PER_J (TPB * VEC)                // 512
#define JITER (COLS_PER_CHUNK / COLS_PER_J)   // 32
#define OUT_SCALE 0.005524271728019903f       // 1/sqrt(32768)
#define LDS_STRIDE 41                         // odd stride -> conflict-free epilogue

// ---------------- stage 0: packed 3-bit angle indices ----------------
// idx[c] = sum_p ((k[2p] | k[2p+1]<<3) << 6p), k[o] = round(w[o][c]) mod 8.
__global__ __launch_bounds__(256) void build_table(const float* __restrict__ w,
                                                   unsigned int* __restrict__ idx) {
    int c = blockIdx.x * blockDim.x + threadIdx.x;
    if (c >= IN_DIM) return;
    unsigned int d = 0;
#pragma unroll
    for (int o = 0; o < CLASSES; ++o) {
        int k = ((int)rintf(w[(size_t)o * IN_DIM + c])) & 7;  // mod 8 (2's compl)
        d |= (unsigned int)k << (3 * o);
    }
    idx[c] = d;
}

// decode 2 packed dwords (2 adjacent columns) + 4-row x 2-col pk_fma block
__device__ __forceinline__ void body(v2u pidx, const v2f* xc,
                                     const v2f* lutC, const v2f* lutS,
                                     v2f acc[RB][5]) {
    v2f ck0[5], sk0[5], ck1[5], sk1[5];
#pragma unroll
    for (int p = 0; p < 5; ++p) {
        unsigned int a = (pidx.x >> (6 * p)) & 63;
        unsigned int b = (pidx.y >> (6 * p)) & 63;
        ck0[p] = lutC[a]; sk0[p] = lutS[a];
        ck1[p] = lutC[b]; sk1[p] = lutS[b];
    }
#pragma unroll
    for (int r = 0; r < RB; ++r) {
        float cx0 = __builtin_amdgcn_cosf(xc[r].x * 0.125f);
        float sx0 = __builtin_amdgcn_sinf(xc[r].x * 0.125f);
        float cx1 = __builtin_amdgcn_cosf(xc[r].y * 0.125f);
        float sx1 = __builtin_amdgcn_sinf(xc[r].y * 0.125f);
        v2f c0 = {cx0, cx0}, s0 = {sx0, sx0};
        v2f c1 = {cx1, cx1}, s1 = {sx1, sx1};
#pragma unroll
        for (int p = 0; p < 5; ++p) {
            acc[r][p] = __builtin_elementwise_fma(
                c0, ck0[p], __builtin_elementwise_fma(s0, sk0[p], acc[r][p]));
            acc[r][p] = __builtin_elementwise_fma(
                c1, ck1[p], __builtin_elementwise_fma(s1, sk1[p], acc[r][p]));
        }
    }
}

// ---------------- stage 1: main streaming kernel ----------------
// R10 base (NC=2, RB=4, 4 blocks/CU) with ONE change: x staged via
// global_load_lds width-16 — 1 KB/wave contiguous dwordx4 requests (the fill
// kernels' request shape), zero VGPR for x buffers (live ~85 < 128).
// LDS: xbuf 16 KB (dbuf) + LUT 1 KB + scratch 21 KB = 37.5 KB -> 4 blocks/CU.
__global__ __launch_bounds__(256, 4) void gsim_main(const float* __restrict__ x,
                                                    const unsigned int* __restrict__ idx,
                                                    float* __restrict__ part) {
    __shared__ float xlds[2][RB][COLS_PER_J];     // 16 KB double-buffered x tile
    __shared__ v2f lutC[64], lutS[64];            // 1 KB angle-pair LUT
    __shared__ float lds[128][LDS_STRIDE];        // 21 KB reduction scratch
    const int chunk = blockIdx.x % NC;
    const int rowblk = blockIdx.x / NC;
    const int tid = threadIdx.x;
    const int wv = tid >> 6;                      // wave id 0..3: stages row wv
    const int ln = tid & 63;                      // lane id
    const int row0 = rowblk * RB;
    const int cbase = chunk * COLS_PER_CHUNK;
    const int jstart = (blockIdx.x * 13) & (JITER - 1);   // per-block phase

    // wave wv stages row (row0+wv), slice [CO, CO+512): 2 x 1KB-wide calls,
    // lane l lands at LDS dest + l*16 (wave-uniform dest, linear layout).
#define STAGE(BUF, CO)                                                         \
    do {                                                                       \
        const float* g0 = x + (size_t)(row0 + wv) * IN_DIM + cbase + (CO) +    \
                          ln * 4;                                              \
        __builtin_amdgcn_global_load_lds(                                      \
            (const __attribute__((address_space(1))) unsigned int*)g0,         \
            (__attribute__((address_space(3))) unsigned int*)&xlds[BUF][wv][0],\
            16, 0, 0);                                                         \
        __builtin_amdgcn_global_load_lds(                                      \
            (const __attribute__((address_space(1))) unsigned int*)(g0 + 256), \
            (__attribute__((address_space(3))) unsigned int*)&xlds[BUF][wv][256],\
            16, 0, 0);                                                         \
    } while (0)

    if (tid < 64) {
        lutC[tid] = (v2f){__builtin_amdgcn_cosf((tid & 7) * 0.125f),
                          __builtin_amdgcn_cosf((tid >> 3) * 0.125f)};
        lutS[tid] = (v2f){__builtin_amdgcn_sinf((tid & 7) * 0.125f),
                          __builtin_amdgcn_sinf((tid >> 3) * 0.125f)};
    }

    v2f acc[RB][5];
#pragma unroll
    for (int r = 0; r < RB; ++r)
#pragma unroll
        for (int p = 0; p < 5; ++p) acc[r][p] = (v2f){0.f, 0.f};

    const unsigned int* ibase = idx + cbase + VEC * tid;

    // prologue: stage j-slot 0 into buf 0
    const int co0 = jstart * COLS_PER_J;
    STAGE(0, co0);
    v2u iA = *(const v2u*)(ibase + co0);
    __syncthreads();                              // LUT + buf0 ready

    int buf = 0;
#pragma unroll 1
    for (int t = 0; t < JITER; ++t) {
        v2u iN = iA;
        if (t + 1 < JITER) {                      // uniform branch
            const int con = ((jstart + t + 1) & (JITER - 1)) * COLS_PER_J;
            STAGE(buf ^ 1, con);                  // prefetch next slice -> other buf
            iN = *(const v2u*)(ibase + con);
        }
        // compute from current buffer: 4x ds_read_b64 (2-bank-pair, free)
        v2f xr[RB];
#pragma unroll
        for (int r = 0; r < RB; ++r)
            xr[r] = *(const v2f*)&xlds[buf][r][VEC * tid];
        body(iA, xr, lutC, lutS, acc);
        __syncthreads();                          // reads done + next stage landed
        buf ^= 1;
        iA = iN;
    }
#undef STAGE

    // ---- block reduction: 256 threads -> 40 partial sums ----
    const float* af = (const float*)acc;          // 40 floats, (r, class) order
    if (tid >= 128) {
#pragma unroll
        for (int v = 0; v < RB * CLASSES; ++v)
            lds[tid - 128][v] = af[v];
    }
    __syncthreads();
    if (tid < 128) {
#pragma unroll
        for (int v = 0; v < RB * CLASSES; ++v)
            lds[tid][v] = af[v] + lds[tid][v];
    }
    __syncthreads();
    // 40 collectors, stride 41 -> conflict-free; fixed order (deterministic)
    if (tid < RB * CLASSES) {
        float s = 0.f;
        for (int t = 0; t < 128; ++t) s += lds[t][tid];
        part[(size_t)chunk * (BATCH * CLASSES) + (size_t)row0 * CLASSES + tid] = s;
    }
}

// ---------------- stage 2: fold NC partials + scale ----------------
__global__ __launch_bounds__(256) void reduce_out(const float* __restrict__ part,
                                                  const float* __restrict__ radius,
                                                  float* __restrict__ out) {
    int i = blockIdx.x * blockDim.x + threadIdx.x;
    if (i >= BATCH * CLASSES) return;
    float s = 0.f;
#pragma unroll
    for (int c = 0; c < NC; ++c) s += part[(size_t)c * (BATCH * CLASSES) + i];
    out[i] = s * radius[0] * OUT_SCALE;
}

extern "C" void kernel_launch(void* const* d_in, const int* in_sizes, int n_in,
                              void* d_out, int out_size, void* d_ws, size_t ws_size,
                              hipStream_t stream) {
    const float* x = (const float*)d_in[0];
    const float* w = (const float*)d_in[1];
    const float* radius = (const float*)d_in[2];
    float* out = (float*)d_out;

    unsigned int* tab = (unsigned int*)d_ws;                      // 128 KB
    float* part = (float*)((char*)d_ws + (size_t)IN_DIM * sizeof(unsigned int));
    // part: NC*2048*10 f32 = 160 KB

    build_table<<<IN_DIM / 256, 256, 0, stream>>>(w, tab);
    gsim_main<<<(BATCH / RB) * NC, 256, 0, stream>>>(x, tab, part);
    reduce_out<<<(BATCH * CLASSES + 255) / 256, 256, 0, stream>>>(part, radius, out);
}

// Round 13
// 61.069 us; speedup vs baseline: 1.1928x; 1.1928x over previous
//
#include <hip/hip_runtime.h>

typedef float v2f __attribute__((ext_vector_type(2)));
typedef unsigned int v2u __attribute__((ext_vector_type(2)));

#define IN_DIM 32768
#define BATCH 2048
#define CLASSES 10
#define NC 2                                  // column chunks
#define RB 4                                  // rows per block/thread (fits 128 VGPR)
#define TPB 256
#define VEC 2                                 // columns per thread per j (float2 loads)
#define COLS_PER_CHUNK (IN_DIM / NC)          // 16384
#define COLS_PER_J (TPB * VEC)                // 512
#define JITER (COLS_PER_CHUNK / COLS_PER_J)   // 32
#define OUT_SCALE 0.005524271728019903f       // 1/sqrt(32768)
#define LDS_STRIDE 41                         // odd stride -> conflict-free epilogue

// ---------------- stage 0: packed 3-bit angle indices ----------------
// idx[c] = sum_p ((k[2p] | k[2p+1]<<3) << 6p), k[o] = round(w[o][c]) mod 8.
__global__ __launch_bounds__(256) void build_table(const float* __restrict__ w,
                                                   unsigned int* __restrict__ idx) {
    int c = blockIdx.x * blockDim.x + threadIdx.x;
    if (c >= IN_DIM) return;
    unsigned int d = 0;
#pragma unroll
    for (int o = 0; o < CLASSES; ++o) {
        int k = ((int)rintf(w[(size_t)o * IN_DIM + c])) & 7;  // mod 8 (2's compl)
        d |= (unsigned int)k << (3 * o);
    }
    idx[c] = d;
}

// decode 2 packed dwords (2 adjacent columns) + 4-row x 2-col pk_fma block
__device__ __forceinline__ void body(v2u pidx, const v2f* xc,
                                     const v2f* lutC, const v2f* lutS,
                                     v2f acc[RB][5]) {
    v2f ck0[5], sk0[5], ck1[5], sk1[5];
#pragma unroll
    for (int p = 0; p < 5; ++p) {
        unsigned int a = (pidx.x >> (6 * p)) & 63;
        unsigned int b = (pidx.y >> (6 * p)) & 63;
        ck0[p] = lutC[a]; sk0[p] = lutS[a];
        ck1[p] = lutC[b]; sk1[p] = lutS[b];
    }
#pragma unroll
    for (int r = 0; r < RB; ++r) {
        float cx0 = __builtin_amdgcn_cosf(xc[r].x * 0.125f);
        float sx0 = __builtin_amdgcn_sinf(xc[r].x * 0.125f);
        float cx1 = __builtin_amdgcn_cosf(xc[r].y * 0.125f);
        float sx1 = __builtin_amdgcn_sinf(xc[r].y * 0.125f);
        v2f c0 = {cx0, cx0}, s0 = {sx0, sx0};
        v2f c1 = {cx1, cx1}, s1 = {sx1, sx1};
#pragma unroll
        for (int p = 0; p < 5; ++p) {
            acc[r][p] = __builtin_elementwise_fma(
                c0, ck0[p], __builtin_elementwise_fma(s0, sk0[p], acc[r][p]));
            acc[r][p] = __builtin_elementwise_fma(
                c1, ck1[p], __builtin_elementwise_fma(s1, sk1[p], acc[r][p]));
        }
    }
}

// CO = column offset (elements) of the j-slot to load
#define LOADBUF(XB, IB, CO)                                                    \
    do {                                                                       \
        IB = *(const v2u*)(ibase + (CO));                                      \
        _Pragma("unroll")                                                      \
        for (int r = 0; r < RB; ++r)                                           \
            XB[r] = *(const v2f*)(xbase + (size_t)r * IN_DIM + (CO));          \
    } while (0)

// ---------------- stage 1: main streaming kernel ----------------
// BEST-MEASURED CONFIG (R10, 63.1 us): grid = 1024 = exactly 4 blocks/CU
// (16 waves/CU), RB=4 keeps live VGPR ~104 < 128, LDS 21 KB x 4 = 84 <= 160.
// Depth-2 pipeline, per-block phase rotation. Measured ~4.7 TB/s on the
// 257 MB x stream = 75% of copy ceiling; 7 orthogonal levers (NT, depth,
// phase, width, TLP, fusion, LDS-staging) all null/negative -> roofline
// for this 4096-stream x 2KB-granule row-gather shape.
__global__ __launch_bounds__(256, 4) void gsim_main(const float* __restrict__ x,
                                                    const unsigned int* __restrict__ idx,
                                                    float* __restrict__ part) {
    __shared__ v2f lutC[64], lutS[64];            // 1 KB angle-pair LUT
    __shared__ float lds[128][LDS_STRIDE];        // 21 KB reduction scratch
    const int chunk = blockIdx.x % NC;
    const int rowblk = blockIdx.x / NC;
    const int tid = threadIdx.x;
    const int row0 = rowblk * RB;
    const int cbase = chunk * COLS_PER_CHUNK;
    const int jstart = (blockIdx.x * 13) & (JITER - 1);   // per-block phase

    if (tid < 64) {
        lutC[tid] = (v2f){__builtin_amdgcn_cosf((tid & 7) * 0.125f),
                          __builtin_amdgcn_cosf((tid >> 3) * 0.125f)};
        lutS[tid] = (v2f){__builtin_amdgcn_sinf((tid & 7) * 0.125f),
                          __builtin_amdgcn_sinf((tid >> 3) * 0.125f)};
    }
    __syncthreads();   // before prefetch: barrier's vmcnt(0) can't flush it

    v2f acc[RB][5];
#pragma unroll
    for (int r = 0; r < RB; ++r)
#pragma unroll
        for (int p = 0; p < 5; ++p) acc[r][p] = (v2f){0.f, 0.f};

    const float* xbase = x + (size_t)row0 * IN_DIM + cbase + VEC * tid;
    const unsigned int* ibase = idx + cbase + VEC * tid;

    // prologue: prefetch phases t=0 (A) and t=1 (B)
    v2f xA[RB], xB[RB];
    v2u iA, iB;
    LOADBUF(xA, iA, ((jstart) & (JITER - 1)) * COLS_PER_J);
    LOADBUF(xB, iB, ((jstart + 1) & (JITER - 1)) * COLS_PER_J);

    for (int t = 0; t + 2 < JITER; t += 2) {
        body(iA, xA, lutC, lutS, acc);
        LOADBUF(xA, iA, ((jstart + t + 2) & (JITER - 1)) * COLS_PER_J);

        body(iB, xB, lutC, lutS, acc);
        LOADBUF(xB, iB, ((jstart + t + 3) & (JITER - 1)) * COLS_PER_J);
    }
    body(iA, xA, lutC, lutS, acc);                // t = JITER-2
    body(iB, xB, lutC, lutS, acc);                // t = JITER-1

    // ---- block reduction: 256 threads -> 40 partial sums ----
    const float* af = (const float*)acc;          // 40 floats, (r, class) order
    if (tid >= 128) {
#pragma unroll
        for (int v = 0; v < RB * CLASSES; ++v)
            lds[tid - 128][v] = af[v];
    }
    __syncthreads();
    if (tid < 128) {
#pragma unroll
        for (int v = 0; v < RB * CLASSES; ++v)
            lds[tid][v] = af[v] + lds[tid][v];
    }
    __syncthreads();
    // 40 collectors, stride 41 -> conflict-free; fixed order (deterministic)
    if (tid < RB * CLASSES) {
        float s = 0.f;
        for (int t = 0; t < 128; ++t) s += lds[t][tid];
        part[(size_t)chunk * (BATCH * CLASSES) + (size_t)row0 * CLASSES + tid] = s;
    }
}

// ---------------- stage 2: fold NC partials + scale ----------------
__global__ __launch_bounds__(256) void reduce_out(const float* __restrict__ part,
                                                  const float* __restrict__ radius,
                                                  float* __restrict__ out) {
    int i = blockIdx.x * blockDim.x + threadIdx.x;
    if (i >= BATCH * CLASSES) return;
    float s = 0.f;
#pragma unroll
    for (int c = 0; c < NC; ++c) s += part[(size_t)c * (BATCH * CLASSES) + i];
    out[i] = s * radius[0] * OUT_SCALE;
}

extern "C" void kernel_launch(void* const* d_in, const int* in_sizes, int n_in,
                              void* d_out, int out_size, void* d_ws, size_t ws_size,
                              hipStream_t stream) {
    const float* x = (const float*)d_in[0];
    const float* w = (const float*)d_in[1];
    const float* radius = (const float*)d_in[2];
    float* out = (float*)d_out;

    unsigned int* tab = (unsigned int*)d_ws;                      // 128 KB
    float* part = (float*)((char*)d_ws + (size_t)IN_DIM * sizeof(unsigned int));
    // part: NC*2048*10 f32 = 160 KB

    build_table<<<IN_DIM / 256, 256, 0, stream>>>(w, tab);
    gsim_main<<<(BATCH / RB) * NC, 256, 0, stream>>>(x, tab, part);
    reduce_out<<<(BATCH * CLASSES + 255) / 256, 256, 0, stream>>>(part, radius, out);
}